// Round 7
// baseline (752.213 us; speedup 1.0000x reference)
//
#include <hip/hip_runtime.h>
#include <math.h>

// ---------------------------------------------------------------------------
// RiemannianPooling: logm(eigh) -> mean -> diff_exp -> cov -> cholesky -> bimap
// N=32, M*T*V=3200, C=16, D=136, out 32x64x64 fp32.
// R14: k_logm FROZEN (R13 state; control). Residual attack, all BIT-EXACT:
//  (1) k_cov 8x8 register blocking (was 8x4): b128 per fma -33%; same
//      per-(i,j) accumulation order; hf*77 split keeps 2 blocks/CU.
//  (2) k_chol single-barrier: updaters compute cis=T[i][k]*rinv themselves
//      (same exprs/bits as old ck[]); factor scaled at write-out with
//      1/sqrtf(diag_raw) (identical to in-loop rinv). 272->137 barriers.
//  (3) k_tail = fused tout+bimap, column-split by q-slice (Tout columns are
//      independent); same ascending-j/i sum order; kills a launch + TT
//      round-trip + the 17-row serial staging chain.
// ---------------------------------------------------------------------------

#define EPSV 1e-4f
#define NSWEEP_BIG 6
#define NSWEEP_SMALL 10
#define SQRT2F 1.41421356237309515f

// workspace layout (float offsets) — total 66.5 MB
#define OFF_G      0            // 136
#define OFF_WBT    160          // 137*64 = 8768
#define OFF_MEAN   8960         // 32*136
#define OFF_XM     13312        // 32*136
#define OFF_TR     17664        // 32*2 (tr, 1/tr)
#define OFF_CT     17792        // 32*9320 tri-packed cholesky factor (ends 316032)
#define OFF_MPART  320000       // 6400*136 (aliases head of PART)
#define OFF_PART   320000       // 8*32*9316 (written after MPART consumed)
#define OFF_L      2704896      // 102400*136

typedef float v2f __attribute__((ext_vector_type(2)));

__device__ __forceinline__ float rcp_f(float x){ return __builtin_amdgcn_rcpf(x); }
__device__ __forceinline__ float rsq_f(float x){ return __builtin_amdgcn_rsqf(x); }

// Packed fp32 (VOP3P). Only profitable where operands already flow as pairs
// (R11 post-mortem: scalar-consumed halves force v_mov marshaling).
__device__ __forceinline__ v2f pk_fma(v2f a, v2f b, v2f c){
    v2f d;
    asm("v_pk_fma_f32 %0, %1, %2, %3" : "=v"(d) : "v"(a), "v"(b), "v"(c));
    return d;
}
__device__ __forceinline__ v2f pk_mul(v2f a, v2f b){
    v2f d;
    asm("v_pk_mul_f32 %0, %1, %2" : "=v"(d) : "v"(a), "v"(b));
    return d;
}

// XOR within 16-lane rows via single DPP (VALU pipe).
template<int R>
__device__ __forceinline__ float xl(float x){
    int s = __float_as_int(x);
    if constexpr (R == 1){
        return __int_as_float(__builtin_amdgcn_update_dpp(s, s, 0xB1, 0xF, 0xF, false));
    } else if constexpr (R == 2){
        return __int_as_float(__builtin_amdgcn_update_dpp(s, s, 0x4E, 0xF, 0xF, false));
    } else if constexpr (R == 3){
        return __int_as_float(__builtin_amdgcn_update_dpp(s, s, 0x1B, 0xF, 0xF, false));
    } else if constexpr (R == 7){
        return __int_as_float(__builtin_amdgcn_update_dpp(s, s, 0x141, 0xF, 0xF, false));
    } else if constexpr (R == 8){
        return __int_as_float(__builtin_amdgcn_update_dpp(s, s, 0x128, 0xF, 0xF, false));
    } else {  // R == 15
        return __int_as_float(__builtin_amdgcn_update_dpp(s, s, 0x140, 0xF, 0xF, false));
    }
}

// Pipe split: masks {4,5,6,9..14} -> DS crossbar; {1,2,3,7,8,15} on VALU DPP.
// (R9 post-mortem: DO NOT convert the DS ones to 2-DPP compositions — at
// high VALU pressure with multi-wave occupancy the crossbar ops are free, and
// the composition adds ~30% VALU issue -> 375->540us regression.)
template<int R>
__device__ __forceinline__ float shuf(float x){
    if constexpr ((R >= 4 && R <= 6) || R >= 9){
        constexpr int IMM = (R << 10) | 0x1F;   // BitMode: xor=R, and=0x1F
        return __int_as_float(__builtin_amdgcn_ds_swizzle(__float_as_int(x), IMM));
    } else {
        return xl<R>(x);
    }
}

// decode linear lower-tri index d -> (r,c), d = r(r+1)/2 + c
__device__ __forceinline__ void tri_rc(int d, int &r, int &c){
    int rr = (int)floorf((sqrtf(fmaf(8.f, (float)d, 1.f)) - 1.f) * 0.5f);
    if (rr*(rr+1)/2 > d) rr--;
    if ((rr+1)*(rr+2)/2 <= d) rr++;
    r = rr; c = d - rr*(rr+1)/2;
}

// One XOR-tournament round of one-sided Jacobi. 16 lanes per matrix.
// Rotation from (d = nrm-pn, gam) with 2 rsq; per-lane sign automatic
// (d antisymmetric across the pair); wave-uniform noise-floor skip.
// Returns nonzero iff a rotation was applied (wave-uniform).
template<int R, bool WV>
__device__ __forceinline__ int jac_round(v2f* b, v2f* v, float &nrm, int t){
    v2f pc[8];
#pragma unroll
    for (int i = 0; i < 8; ++i){ pc[i].x = shuf<R>(b[i].x); pc[i].y = shuf<R>(b[i].y); }
    float pn = shuf<R>(nrm);
    // Gram dot: 8 pk_fma in 2 chains (4-deep) instead of 16 scalar fma.
    v2f ga = pk_mul(b[0], pc[0]);
    v2f gb = pk_mul(b[1], pc[1]);
    ga = pk_fma(b[2], pc[2], ga); gb = pk_fma(b[3], pc[3], gb);
    ga = pk_fma(b[4], pc[4], ga); gb = pk_fma(b[5], pc[5], gb);
    ga = pk_fma(b[6], pc[6], ga); gb = pk_fma(b[7], pc[7], gb);
    float gam = (ga.x + gb.x) + (ga.y + gb.y);
    // adaptive skip: |gam| <= 4e-7*sqrt(nrm*pn) is update-noise level; if every
    // pair in the wave (4 matrices) is there, the rotations are identity-level.
    bool live = (gam*gam > 1.6e-13f * (nrm * pn));
    int lv = __any((int)live);
    if (lv){
        constexpr int HB = (R & 8) ? 8 : ((R & 4) ? 4 : ((R & 2) ? 2 : 1));
        const bool isp = ((t & HB) == 0);
        // antisymmetric tie-break: if nrm==pn exactly, d still has opposite
        // signs in the two lanes of a pair.
        float d = (nrm - pn) + (isp ? 1e-30f : -1e-30f);
        float g22 = gam + gam;
        float nrr = fmaf(g22, g22, d*d);
        float inv_r = rsq_f(nrr);                      // 1/sqrt(d^2+4g^2)
        float c2 = fmaf(0.5f*fabsf(d), inv_r, 0.5f);   // cos^2(theta), >= 0.5
        float cinv = rsq_f(c2);
        float smag = fabsf(gam) * inv_r * cinv;        // |sin(theta)|
        int sgn = (__float_as_int(gam) ^ __float_as_int(d)) & 0x80000000;
        bool zn = (nrr == 0.f);                        // fully degenerate pair
        float c = zn ? 1.f : c2 * cinv;
        float s = zn ? 0.f : __int_as_float(__float_as_int(smag) | sgn);
        v2f cv = {c, c};
        v2f sv = {s, s};
#pragma unroll
        for (int i = 0; i < 8; ++i) b[i] = pk_fma(pc[i], sv, pk_mul(b[i], cv));
        if (WV){
            v2f pv[8];
#pragma unroll
            for (int i = 0; i < 8; ++i){ pv[i].x = shuf<R>(v[i].x); pv[i].y = shuf<R>(v[i].y); }
#pragma unroll
            for (int i = 0; i < 8; ++i) v[i] = pk_fma(pv[i], sv, pk_mul(v[i], cv));
        }
        nrm = fmaf(s * cinv, gam, nrm);                // alpha' = alpha + t*gam
    }
    return lv;
}

// Returns nonzero iff any round applied a rotation. If zero, b (and v) are
// bit-identical to sweep entry -> all later sweeps are no-ops (exact break).
template<bool WV>
__device__ __forceinline__ int jac_sweep(v2f* b, v2f* v, float &nrm, int t){
    int lv = 0;
    lv |= jac_round< 4,WV>(b,v,nrm,t); lv |= jac_round< 1,WV>(b,v,nrm,t);
    lv |= jac_round< 5,WV>(b,v,nrm,t); lv |= jac_round< 2,WV>(b,v,nrm,t);
    lv |= jac_round< 6,WV>(b,v,nrm,t); lv |= jac_round< 3,WV>(b,v,nrm,t);
    lv |= jac_round< 9,WV>(b,v,nrm,t); lv |= jac_round< 7,WV>(b,v,nrm,t);
    lv |= jac_round<10,WV>(b,v,nrm,t); lv |= jac_round< 8,WV>(b,v,nrm,t);
    lv |= jac_round<11,WV>(b,v,nrm,t); lv |= jac_round<15,WV>(b,v,nrm,t);
    lv |= jac_round<12,WV>(b,v,nrm,t); lv |= jac_round<13,WV>(b,v,nrm,t);
    lv |= jac_round<14,WV>(b,v,nrm,t);
    return lv;
}

// ---------------------------------------------------------------------------
// B: per-matrix eigh + logm lower triangle + per-block mean partials. (FROZEN)
__global__ __launch_bounds__(256) void k_logm(const float* __restrict__ x,
                                              float* __restrict__ L,
                                              float* __restrict__ mpart,
                                              const float* __restrict__ W,
                                              const float* __restrict__ Wb,
                                              float* __restrict__ ws){
    __shared__ float sm[5120];     // Bl[16][16 rows x 20] with cof in padding
                                   // (20480 B = exactly 160KB/8 -> 8 blocks/CU)
    const int tid = threadIdx.x;
    const int t = tid & 15;
    const int g = tid >> 4;
    if (blockIdx.x == 6400){
        // ---- prep: s = svd(W_sym) desc -> G; WbT transpose ----
        float* sigv  = sm;          // 16
        float* s_srt = sm + 16;     // 16
        if (tid < 64){
            v2f b[8]; float nrm = 0.f;
            float* bf = (float*)b;
#pragma unroll
            for (int i = 0; i < 16; ++i){
                float val = 0.5f * (W[i*16 + t] + W[t*16 + i]);
                bf[i] = val;
                nrm = fmaf(val, val, nrm);
            }
#pragma unroll 1
            for (int sw = 0; sw < NSWEEP_SMALL; ++sw)
                if (!jac_sweep<false>(b, b, nrm, t)) break;
            float n2 = 0.f;
#pragma unroll
            for (int i = 0; i < 16; ++i) n2 = fmaf(bf[i], bf[i], n2);
            float sig = sqrtf(n2);
            if (tid < 16) sigv[t] = sig;
        }
        __syncthreads();
        if (tid < 16){
            float sig = sigv[t];
            int rank = 0;
#pragma unroll
            for (int u = 0; u < 16; ++u){
                float su = sigv[u];
                rank += (su > sig || (su == sig && u < t)) ? 1 : 0;
            }
            s_srt[rank] = sig;   // descending, matches jnp.linalg.svd order
        }
        for (int e = tid; e < 8768; e += 256){
            int o = e / 137, i = e - o*137;
            ws[OFF_WBT + i*64 + o] = Wb[e];
        }
        __syncthreads();
        if (tid < 136){
            int r, c; tri_rc(tid, r, c);
            float sr = s_srt[r], sc = s_srt[c];
            float den = sr - sc;
            bool eq = fabsf(den) < EPSV;
            float er = expf(sr), ec = expf(sc);
            float num = eq ? 0.5f*(er + ec) : (er - ec);
            float dd  = eq ? 1.f : den;
            float scale = (r == c) ? 1.f : SQRT2F;
            ws[OFF_G + tid] = scale * num / dd;
        }
        return;
    }
    float* Bl = sm;                // g*320 + i*20 + t; cof[j] at g*320+(j>>2)*20+16+(j&3)
    const size_t m = (size_t)blockIdx.x * 16 + g;
    const float* xp = x + m * 256;
    v2f b[8]; float nrm = 0.f;
    float* bf = (float*)b;
#pragma unroll
    for (int i = 0; i < 16; ++i){
        float val = xp[i*16 + t];
        bf[i] = val;
        nrm = fmaf(val, val, nrm);
    }
#pragma unroll 1
    for (int sw = 0; sw < NSWEEP_BIG; ++sw)
        if (!jac_sweep<false>(b, b, nrm, t)) break;
    float n2 = 0.f;
#pragma unroll
    for (int i = 0; i < 16; ++i) n2 = fmaf(bf[i], bf[i], n2);
    float lam = sqrtf(n2);
    float w = logf(fmaxf(lam, EPSV));
    float coef = w / n2;            // logm = sum_j coef_j b_j b_j^T
#pragma unroll
    for (int i = 0; i < 16; ++i) Bl[g*320 + i*20 + t] = bf[i];
    Bl[g*320 + (t>>2)*20 + 16 + (t&3)] = coef;   // cof[t] in row-t>>2 padding
    __syncthreads();
    float outv[9];
    float* Lp = L + m * 136;
#pragma unroll
    for (int k = 0; k < 9; ++k){
        int d = t + 16*k;
        float acc = 0.f;
        if (d < 136){
            int r, c; tri_rc(d, r, c);
            const float4* Br = (const float4*)&Bl[g*320 + r*20];
            const float4* Bc = (const float4*)&Bl[g*320 + c*20];
            v2f a2 = {0.f, 0.f};
#pragma unroll
            for (int j4 = 0; j4 < 4; ++j4){
                float4 br = Br[j4], bc = Bc[j4];
                float4 cf = *(const float4*)&Bl[g*320 + j4*20 + 16];
                v2f p1 = pk_mul((v2f){br.x, br.y}, (v2f){cf.x, cf.y});
                a2 = pk_fma(p1, (v2f){bc.x, bc.y}, a2);
                v2f p2 = pk_mul((v2f){br.z, br.w}, (v2f){cf.z, cf.w});
                a2 = pk_fma(p2, (v2f){bc.z, bc.w}, a2);
            }
            acc = a2.x + a2.y;
            Lp[d] = acc;
        }
        outv[k] = acc;
    }
    __syncthreads();
    float* red = sm;                // red[g*144 + d]
#pragma unroll
    for (int k = 0; k < 9; ++k){
        int d = t + 16*k;
        red[g*144 + d] = outv[k];
    }
    __syncthreads();
    if (tid < 136){
        float s = 0.f;
#pragma unroll
        for (int gg = 0; gg < 16; ++gg) s += red[gg*144 + tid];
        mpart[(size_t)blockIdx.x * 136 + tid] = s;
    }
}

// ---------------------------------------------------------------------------
// C: finalize mean from 200 block-partials per n. 3-way c-split (408 threads).
__global__ __launch_bounds__(512) void k_xm_mean(float* __restrict__ ws){
    __shared__ float part[3][136];
    const int n = blockIdx.x;
    const int tid = threadIdx.x;
    const int h = tid / 136;
    const int d = tid - h*136;
    if (tid < 408){
        int c0 = h*67, c1 = (h == 2) ? 200 : (c0 + 67);
        const float* mp = ws + OFF_MPART + (size_t)n * 200 * 136 + d;
        float s = 0.f;
#pragma unroll 4
        for (int c = c0; c < c1; ++c) s += mp[(size_t)c * 136];
        part[h][d] = s;
    }
    __syncthreads();
    if (tid < 136)
        ws[OFF_MEAN + n*136 + tid] =
            ((part[0][tid] + part[1][tid]) + part[2][tid]) * (1.f/3200.f);
}

// ---------------------------------------------------------------------------
// E: blocks 0..511: partial covariance, 8x8 register blocks. Block (n,c8,hf)
//    computes T = hf*77 + tid (T < 153) over its c8 group's 400 samples.
//    Per-(i,j) accumulation order identical to all prior versions.
//    Blocks 512..543: xm eigendecomp.
__global__ __launch_bounds__(256) void k_cov(float* __restrict__ ws){
    __shared__ __align__(16) float xc[16][136];
    __shared__ __align__(16) float Gl[136];
    __shared__ __align__(16) float Ml[136];
    const int bid = blockIdx.x;
    const int tid = threadIdx.x;
    if (bid >= 512){
        const int n = bid - 512;
        float* smf = &xc[0][0];
        float* Ms  = smf;              // 136
        float* Vl  = smf + 144;        // 16*20
        float* Hl2 = smf + 464;        // 16*20
        if (tid < 136) Ms[tid] = ws[OFF_MEAN + n*136 + tid];
        __syncthreads();
        const int t = tid & 15;
        if (tid < 64){
            v2f b[8], v[8]; float nrm = 0.f;
            float* bf = (float*)b;
            float* vf = (float*)v;
#pragma unroll
            for (int i = 0; i < 16; ++i){
                int r = (i > t) ? i : t, c = (i > t) ? t : i;
                bf[i] = Ms[r*(r+1)/2 + c];
                vf[i] = (i == t) ? 1.f : 0.f;
                nrm = fmaf(bf[i], bf[i], nrm);
            }
#pragma unroll 1
            for (int sw = 0; sw < NSWEEP_SMALL; ++sw)
                if (!jac_sweep<true>(b, v, nrm, t)) break;
            float lam = 0.f;
#pragma unroll
            for (int i = 0; i < 16; ++i) lam = fmaf(vf[i], bf[i], lam);  // signed
            float w = logf(fmaxf(lam, EPSV));
            if (tid < 16){
#pragma unroll
                for (int i = 0; i < 16; ++i){ Vl[i*20 + t] = vf[i]; Hl2[i*20 + t] = w * vf[i]; }
            }
        }
        __syncthreads();
        if (tid < 16){
            for (int k = 0; k < 9; ++k){
                int d = t + 16*k;
                if (d < 136){
                    int r, c; tri_rc(d, r, c);
                    float acc = 0.f;
#pragma unroll
                    for (int j = 0; j < 16; ++j) acc = fmaf(Hl2[r*20 + j], Vl[c*20 + j], acc);
                    float scale = (r == c) ? 1.f : SQRT2F;
                    ws[OFF_XM + n*136 + d] = scale * acc;
                }
            }
        }
        return;
    }
    const int n = bid & 31, c8 = (bid >> 5) & 7, hf = bid >> 8;
    if (tid < 136){
        Gl[tid] = ws[OFF_G + tid];
        Ml[tid] = ws[OFF_MEAN + n*136 + tid];
    }
    int bi = 0, bj = 0;
    const int T = hf*77 + tid;
    const bool val = (tid < (hf ? 76 : 77));   // T < 153
    if (val) tri_rc(T, bi, bj);                // T = bi*(bi+1)/2 + bj, bj <= bi
    // accumulators: av[p*8+jj] = {a(2p,jj), a(2p+1,jj)} within the 8x8 block
    v2f av[32];
#pragma unroll
    for (int i = 0; i < 32; ++i) av[i] = (v2f){0.f, 0.f};
    const float* Lbase = ws + OFF_L + (size_t)n * 3200 * 136;
    for (int st = 0; st < 25; ++st){
        __syncthreads();
        int p0 = c8*400 + st*16;
        for (int f = tid; f < 544; f += 256){
            int pp = f / 34, dd = f - pp*34;
            float4 lv = *(const float4*)(Lbase + (size_t)(p0+pp)*136 + dd*4);
            float4 gv = *(const float4*)(&Gl[dd*4]);
            float4 mv = *(const float4*)(&Ml[dd*4]);
            float4 r;
            r.x = (lv.x - mv.x) * gv.x; r.y = (lv.y - mv.y) * gv.y;
            r.z = (lv.z - mv.z) * gv.z; r.w = (lv.w - mv.w) * gv.w;
            *(float4*)(&xc[pp][dd*4]) = r;
        }
        __syncthreads();
        if (val){
#pragma unroll 1
            for (int pp = 0; pp < 16; ++pp){
                const float4 u0 = *(const float4*)(&xc[pp][bi*8]);
                const float4 u1 = *(const float4*)(&xc[pp][bi*8+4]);
                const float4 w0 = *(const float4*)(&xc[pp][bj*8]);
                const float4 w1 = *(const float4*)(&xc[pp][bj*8+4]);
                v2f u01 = {u0.x, u0.y}, u23 = {u0.z, u0.w};
                v2f u45 = {u1.x, u1.y}, u67 = {u1.z, u1.w};
                float wj[8] = {w0.x, w0.y, w0.z, w0.w, w1.x, w1.y, w1.z, w1.w};
#pragma unroll
                for (int jj = 0; jj < 8; ++jj){
                    v2f wb = {wj[jj], wj[jj]};
                    av[0*8+jj] = pk_fma(u01, wb, av[0*8+jj]);
                    av[1*8+jj] = pk_fma(u23, wb, av[1*8+jj]);
                    av[2*8+jj] = pk_fma(u45, wb, av[2*8+jj]);
                    av[3*8+jj] = pk_fma(u67, wb, av[3*8+jj]);
                }
            }
        }
    }
    if (val){
        float* part = ws + OFF_PART + ((size_t)c8*32 + n)*9316;
#pragma unroll
        for (int p = 0; p < 4; ++p){
#pragma unroll
            for (int h = 0; h < 2; ++h){
                int i = bi*8 + p*2 + h;
#pragma unroll
                for (int jj = 0; jj < 8; ++jj){
                    int j = bj*8 + jj;
                    if (j <= i) part[i*(i+1)/2 + j] = av[p*8+jj][h];
                }
            }
        }
    }
}

// ---------------------------------------------------------------------------
// F: sum partials -> cov -> single-barrier Cholesky. Updaters compute
//    cis = T[i][k]*rinv themselves (same bits as the old ck[]); the scaled
//    factor is materialized at write-out with dg/rcol (identical exprs).
#define TST 141   // T row stride: 141 mod 32 = 13, gcd(13,32)=1 -> conflict-free cols
__global__ __launch_bounds__(512) void k_chol(float* __restrict__ ws){
    __shared__ float T[136*TST];    // 76.7 KB (raw columns; scaled at writeout)
    __shared__ float dg[136];       // sqrtf(diag)
    __shared__ float rc2[136];      // 1/sqrtf(diag) == in-loop rinv expr
    const int n = blockIdx.x;
    const int tid = threadIdx.x;
    // stage cov (tri-packed partials -> full lower)
    for (int e = tid; e < 9316; e += 512){
        float s = 0.f;
#pragma unroll
        for (int c = 0; c < 8; ++c) s += ws[OFF_PART + ((size_t)c*32 + n)*9316 + e];
        int r, cc2; tri_rc(e, r, cc2);
        T[r*TST + cc2] = s * (1.f/3199.f);
    }
    __syncthreads();
    // right-looking Cholesky, ONE barrier per k. Column k is read-only raw
    // during iteration k; trailing writes are to columns >= k+1 (disjoint).
    for (int k = 0; k < 135; ++k){
        float dkk = sqrtf(T[k*TST + k]);
        float rinv = 1.f / dkk;
        const int m = 135 - k;
        const int cnt = m*(m+1)/2;
        const int Lc = (cnt + 511) >> 9;
        int e0 = tid * Lc, e1 = e0 + Lc; if (e1 > cnt) e1 = cnt;
        if (e0 < e1){
            float A = 2.f*m + 1.f;
            int jp = (int)floorf((A - sqrtf(fmaf(A, A, -8.f*e0))) * 0.5f);
            if (jp < 0) jp = 0;
            while (jp > 0 && jp*m - jp*(jp-1)/2 > e0) jp--;
            while ((jp+1)*m - (jp+1)*jp/2 <= e0) jp++;
            int ip = jp + (e0 - (jp*m - jp*(jp-1)/2));
            int i = k+1+ip, j = k+1+jp;
            int ix = i*TST + j;
            int e = e0;
            while (e < e1){
                int nb = e1 - e; if (nb > 8) nb = 8;
                int   ixs[8]; float cis[8], cjs[8], tv[8];
#pragma unroll
                for (int b2 = 0; b2 < 8; ++b2){
                    if (b2 < nb){
                        ixs[b2] = ix;
                        cis[b2] = T[i*TST + k] * rinv;   // == old ck[i]
                        cjs[b2] = T[j*TST + k] * rinv;   // == old ck[j]
                        i++; ix += TST;
                        if (i == 136){ j++; i = j; ix = i*TST + j; }
                    }
                }
#pragma unroll
                for (int b2 = 0; b2 < 8; ++b2) if (b2 < nb) tv[b2] = T[ixs[b2]];
#pragma unroll
                for (int b2 = 0; b2 < 8; ++b2) if (b2 < nb) tv[b2] = fmaf(-cis[b2], cjs[b2], tv[b2]);
#pragma unroll
                for (int b2 = 0; b2 < 8; ++b2) if (b2 < nb) T[ixs[b2]] = tv[b2];
                e += nb;
            }
        }
        __syncthreads();
    }
    // diag sqrt + per-column scale (identical expressions to in-loop values)
    if (tid < 136){
        float d = sqrtf(T[tid*TST + tid]);
        dg[tid] = d;
        rc2[tid] = 1.f / d;
    }
    __syncthreads();
    if (tid == 0){
        float tr = 1.f;
        for (int kk = 0; kk < 136; ++kk) tr += dg[kk];
        ws[OFF_TR + n*2]     = tr;
        ws[OFF_TR + n*2 + 1] = 1.f / tr;
    }
    // write tri-packed scaled factor
    for (int e = tid; e < 9316; e += 512){
        int r, c; tri_rc(e, r, c);
        float v = (r == c) ? dg[c] : T[r*TST + c] * rc2[c];
        ws[OFF_CT + (size_t)n*9320 + e] = v;
    }
}

// ---------------------------------------------------------------------------
// F2: fused Tout+bimap, column-split. Block (n, qs) computes Tout columns
//     q = qs*8..qs*8+7 for ALL rows i (Tout cols are independent), then the
//     bimap slice out[n][all o][those q]. Same ascending-j / ascending-i
//     summation order as the old k_tout/k_bimap (bit-identical).
__global__ __launch_bounds__(512) void k_tail(float* __restrict__ ws,
                                              const float* __restrict__ Wb,
                                              float* __restrict__ out){
    __shared__ float ct[9320];      // tri-packed factor; reused for Wb rows
    __shared__ float wt8[1096];     // WbT q-slice: [j*8+ql]
    __shared__ float tt8[1096];     // Tout slice:  [i*8+ql]
    __shared__ float xs[137];
    const int bid = blockIdx.x;
    const int n = bid >> 3, qs = bid & 7;
    const int tid = threadIdx.x;
    const float* ctg = ws + OFF_CT + (size_t)n * 9320;
    for (int e = tid; e < 9316; e += 512) ct[e] = ctg[e];
    for (int e = tid; e < 1096; e += 512){
        int j = e >> 3, ql = e & 7;
        wt8[e] = ws[OFF_WBT + j*64 + qs*8 + ql];
    }
    if (tid < 137) xs[tid] = (tid < 136) ? ws[OFF_XM + n*136 + tid] : 1.f;
    __syncthreads();
    const float tr  = ws[OFF_TR + n*2];
    const float itr = ws[OFF_TR + n*2 + 1];
    const float c6 = tr * 1e-6f;
    for (int task = tid; task < 1096; task += 512){
        int i = task >> 3, ql = task & 7;
        if (i < 136){
            const float* cr = ct + i*(i+1)/2;
            float acc = 0.f;
            for (int j = 0; j <= i; ++j) acc = fmaf(cr[j], wt8[j*8 + ql], acc);
            tt8[task] = fmaf(c6, wt8[i*8 + ql], itr * acc);
        } else {
            float acc = wt8[136*8 + ql];       // out[D][D] = 1 term first
            for (int j = 0; j < 136; ++j) acc = fmaf(xs[j], wt8[j*8 + ql], acc);
            tt8[task] = fmaf(c6, wt8[136*8 + ql], itr * acc);
        }
    }
    __syncthreads();
    // ct dead -> reuse for Wb rows [o*137 + i]
    for (int e = tid; e < 8768; e += 512) ct[e] = Wb[e];
    __syncthreads();
    const int o = tid >> 3, ql = tid & 7;
    const float* wr = ct + o*137;
    float acc = 0.f;
    for (int i = 0; i <= 136; ++i) acc = fmaf(wr[i], tt8[i*8 + ql], acc);
    out[(size_t)n*4096 + o*64 + qs*8 + ql] = acc;
}

// ---------------------------------------------------------------------------
extern "C" void kernel_launch(void* const* d_in, const int* in_sizes, int n_in,
                              void* d_out, int out_size, void* d_ws, size_t ws_size,
                              hipStream_t stream){
    const float* x   = (const float*)d_in[0];
    const float* W   = (const float*)d_in[1];
    const float* Wb  = (const float*)d_in[2];
    float* out = (float*)d_out;
    float* ws  = (float*)d_ws;

    k_logm   <<<6401, 256, 0, stream>>>(x, ws + OFF_L, ws + OFF_MPART, W, Wb, ws);
    k_xm_mean<<<  32, 512, 0, stream>>>(ws);
    k_cov    <<< 544, 256, 0, stream>>>(ws);
    k_chol   <<<  32, 512, 0, stream>>>(ws);
    k_tail   <<< 256, 512, 0, stream>>>(ws, Wb, out);
}

// Round 9
// 711.933 us; speedup vs baseline: 1.0566x; 1.0566x over previous
//
#include <hip/hip_runtime.h>
#include <math.h>

// ---------------------------------------------------------------------------
// RiemannianPooling: logm(eigh) -> mean -> diff_exp -> cov -> cholesky -> bimap
// N=32, M*T*V=3200, C=16, D=136, out 32x64x64 fp32.
// R16 == R15 resubmitted verbatim (R15 bench was an infra failure: container
// died twice, no kernel signal). R15 rationale:
//  - k_cov: REVERT to R13 (8x4 tiles, 153/256 active; R14's 8x8 cut active
//    lanes to 77/256 + 64 accum VGPRs -> issue-coverage regression).
//  - k_chol: KEEP R14 single-barrier (bit-exact, 272->137 barriers).
//  - k_tail: KEEP fusion but layouts -> [ql*140+j] (16B-aligned stride-1 rows)
//    so Tout reads merge to b128 and bimap uses float4 single-chain dots
//    (same ascending accumulation order as old k_bimap -> bit-identical).
//  - k_logm FROZEN (control, ~357us).
// ---------------------------------------------------------------------------

#define EPSV 1e-4f
#define NSWEEP_BIG 6
#define NSWEEP_SMALL 10
#define SQRT2F 1.41421356237309515f

// workspace layout (float offsets) — total 66.5 MB
#define OFF_G      0            // 136
#define OFF_WBT    160          // 137*64 = 8768
#define OFF_MEAN   8960         // 32*136
#define OFF_XM     13312        // 32*136
#define OFF_TR     17664        // 32*2 (tr, 1/tr)
#define OFF_CT     17792        // 32*9320 tri-packed cholesky factor (ends 316032)
#define OFF_MPART  320000       // 6400*136 (aliases head of PART)
#define OFF_PART   320000       // 8*32*9316 (written after MPART consumed)
#define OFF_L      2704896      // 102400*136

typedef float v2f __attribute__((ext_vector_type(2)));

__device__ __forceinline__ float rcp_f(float x){ return __builtin_amdgcn_rcpf(x); }
__device__ __forceinline__ float rsq_f(float x){ return __builtin_amdgcn_rsqf(x); }

// Packed fp32 (VOP3P). Only profitable where operands already flow as pairs
// (R11 post-mortem: scalar-consumed halves force v_mov marshaling).
__device__ __forceinline__ v2f pk_fma(v2f a, v2f b, v2f c){
    v2f d;
    asm("v_pk_fma_f32 %0, %1, %2, %3" : "=v"(d) : "v"(a), "v"(b), "v"(c));
    return d;
}
__device__ __forceinline__ v2f pk_mul(v2f a, v2f b){
    v2f d;
    asm("v_pk_mul_f32 %0, %1, %2" : "=v"(d) : "v"(a), "v"(b));
    return d;
}

// XOR within 16-lane rows via single DPP (VALU pipe).
template<int R>
__device__ __forceinline__ float xl(float x){
    int s = __float_as_int(x);
    if constexpr (R == 1){
        return __int_as_float(__builtin_amdgcn_update_dpp(s, s, 0xB1, 0xF, 0xF, false));
    } else if constexpr (R == 2){
        return __int_as_float(__builtin_amdgcn_update_dpp(s, s, 0x4E, 0xF, 0xF, false));
    } else if constexpr (R == 3){
        return __int_as_float(__builtin_amdgcn_update_dpp(s, s, 0x1B, 0xF, 0xF, false));
    } else if constexpr (R == 7){
        return __int_as_float(__builtin_amdgcn_update_dpp(s, s, 0x141, 0xF, 0xF, false));
    } else if constexpr (R == 8){
        return __int_as_float(__builtin_amdgcn_update_dpp(s, s, 0x128, 0xF, 0xF, false));
    } else {  // R == 15
        return __int_as_float(__builtin_amdgcn_update_dpp(s, s, 0x140, 0xF, 0xF, false));
    }
}

// Pipe split: masks {4,5,6,9..14} -> DS crossbar; {1,2,3,7,8,15} on VALU DPP.
// (R9 post-mortem: DO NOT convert the DS ones to 2-DPP compositions — at
// high VALU pressure with multi-wave occupancy the crossbar ops are free, and
// the composition adds ~30% VALU issue -> 375->540us regression.)
template<int R>
__device__ __forceinline__ float shuf(float x){
    if constexpr ((R >= 4 && R <= 6) || R >= 9){
        constexpr int IMM = (R << 10) | 0x1F;   // BitMode: xor=R, and=0x1F
        return __int_as_float(__builtin_amdgcn_ds_swizzle(__float_as_int(x), IMM));
    } else {
        return xl<R>(x);
    }
}

// decode linear lower-tri index d -> (r,c), d = r(r+1)/2 + c
__device__ __forceinline__ void tri_rc(int d, int &r, int &c){
    int rr = (int)floorf((sqrtf(fmaf(8.f, (float)d, 1.f)) - 1.f) * 0.5f);
    if (rr*(rr+1)/2 > d) rr--;
    if ((rr+1)*(rr+2)/2 <= d) rr++;
    r = rr; c = d - rr*(rr+1)/2;
}

// One XOR-tournament round of one-sided Jacobi. 16 lanes per matrix.
// Rotation from (d = nrm-pn, gam) with 2 rsq; per-lane sign automatic
// (d antisymmetric across the pair); wave-uniform noise-floor skip.
// Returns nonzero iff a rotation was applied (wave-uniform).
template<int R, bool WV>
__device__ __forceinline__ int jac_round(v2f* b, v2f* v, float &nrm, int t){
    v2f pc[8];
#pragma unroll
    for (int i = 0; i < 8; ++i){ pc[i].x = shuf<R>(b[i].x); pc[i].y = shuf<R>(b[i].y); }
    float pn = shuf<R>(nrm);
    // Gram dot: 8 pk_fma in 2 chains (4-deep) instead of 16 scalar fma.
    v2f ga = pk_mul(b[0], pc[0]);
    v2f gb = pk_mul(b[1], pc[1]);
    ga = pk_fma(b[2], pc[2], ga); gb = pk_fma(b[3], pc[3], gb);
    ga = pk_fma(b[4], pc[4], ga); gb = pk_fma(b[5], pc[5], gb);
    ga = pk_fma(b[6], pc[6], ga); gb = pk_fma(b[7], pc[7], gb);
    float gam = (ga.x + gb.x) + (ga.y + gb.y);
    // adaptive skip: |gam| <= 4e-7*sqrt(nrm*pn) is update-noise level; if every
    // pair in the wave (4 matrices) is there, the rotations are identity-level.
    bool live = (gam*gam > 1.6e-13f * (nrm * pn));
    int lv = __any((int)live);
    if (lv){
        constexpr int HB = (R & 8) ? 8 : ((R & 4) ? 4 : ((R & 2) ? 2 : 1));
        const bool isp = ((t & HB) == 0);
        // antisymmetric tie-break: if nrm==pn exactly, d still has opposite
        // signs in the two lanes of a pair.
        float d = (nrm - pn) + (isp ? 1e-30f : -1e-30f);
        float g22 = gam + gam;
        float nrr = fmaf(g22, g22, d*d);
        float inv_r = rsq_f(nrr);                      // 1/sqrt(d^2+4g^2)
        float c2 = fmaf(0.5f*fabsf(d), inv_r, 0.5f);   // cos^2(theta), >= 0.5
        float cinv = rsq_f(c2);
        float smag = fabsf(gam) * inv_r * cinv;        // |sin(theta)|
        int sgn = (__float_as_int(gam) ^ __float_as_int(d)) & 0x80000000;
        bool zn = (nrr == 0.f);                        // fully degenerate pair
        float c = zn ? 1.f : c2 * cinv;
        float s = zn ? 0.f : __int_as_float(__float_as_int(smag) | sgn);
        v2f cv = {c, c};
        v2f sv = {s, s};
#pragma unroll
        for (int i = 0; i < 8; ++i) b[i] = pk_fma(pc[i], sv, pk_mul(b[i], cv));
        if (WV){
            v2f pv[8];
#pragma unroll
            for (int i = 0; i < 8; ++i){ pv[i].x = shuf<R>(v[i].x); pv[i].y = shuf<R>(v[i].y); }
#pragma unroll
            for (int i = 0; i < 8; ++i) v[i] = pk_fma(pv[i], sv, pk_mul(v[i], cv));
        }
        nrm = fmaf(s * cinv, gam, nrm);                // alpha' = alpha + t*gam
    }
    return lv;
}

// Returns nonzero iff any round applied a rotation. If zero, b (and v) are
// bit-identical to sweep entry -> all later sweeps are no-ops (exact break).
template<bool WV>
__device__ __forceinline__ int jac_sweep(v2f* b, v2f* v, float &nrm, int t){
    int lv = 0;
    lv |= jac_round< 4,WV>(b,v,nrm,t); lv |= jac_round< 1,WV>(b,v,nrm,t);
    lv |= jac_round< 5,WV>(b,v,nrm,t); lv |= jac_round< 2,WV>(b,v,nrm,t);
    lv |= jac_round< 6,WV>(b,v,nrm,t); lv |= jac_round< 3,WV>(b,v,nrm,t);
    lv |= jac_round< 9,WV>(b,v,nrm,t); lv |= jac_round< 7,WV>(b,v,nrm,t);
    lv |= jac_round<10,WV>(b,v,nrm,t); lv |= jac_round< 8,WV>(b,v,nrm,t);
    lv |= jac_round<11,WV>(b,v,nrm,t); lv |= jac_round<15,WV>(b,v,nrm,t);
    lv |= jac_round<12,WV>(b,v,nrm,t); lv |= jac_round<13,WV>(b,v,nrm,t);
    lv |= jac_round<14,WV>(b,v,nrm,t);
    return lv;
}

// ---------------------------------------------------------------------------
// B: per-matrix eigh + logm lower triangle + per-block mean partials. (FROZEN)
__global__ __launch_bounds__(256) void k_logm(const float* __restrict__ x,
                                              float* __restrict__ L,
                                              float* __restrict__ mpart,
                                              const float* __restrict__ W,
                                              const float* __restrict__ Wb,
                                              float* __restrict__ ws){
    __shared__ float sm[5120];     // Bl[16][16 rows x 20] with cof in padding
                                   // (20480 B = exactly 160KB/8 -> 8 blocks/CU)
    const int tid = threadIdx.x;
    const int t = tid & 15;
    const int g = tid >> 4;
    if (blockIdx.x == 6400){
        // ---- prep: s = svd(W_sym) desc -> G; WbT transpose ----
        float* sigv  = sm;          // 16
        float* s_srt = sm + 16;     // 16
        if (tid < 64){
            v2f b[8]; float nrm = 0.f;
            float* bf = (float*)b;
#pragma unroll
            for (int i = 0; i < 16; ++i){
                float val = 0.5f * (W[i*16 + t] + W[t*16 + i]);
                bf[i] = val;
                nrm = fmaf(val, val, nrm);
            }
#pragma unroll 1
            for (int sw = 0; sw < NSWEEP_SMALL; ++sw)
                if (!jac_sweep<false>(b, b, nrm, t)) break;
            float n2 = 0.f;
#pragma unroll
            for (int i = 0; i < 16; ++i) n2 = fmaf(bf[i], bf[i], n2);
            float sig = sqrtf(n2);
            if (tid < 16) sigv[t] = sig;
        }
        __syncthreads();
        if (tid < 16){
            float sig = sigv[t];
            int rank = 0;
#pragma unroll
            for (int u = 0; u < 16; ++u){
                float su = sigv[u];
                rank += (su > sig || (su == sig && u < t)) ? 1 : 0;
            }
            s_srt[rank] = sig;   // descending, matches jnp.linalg.svd order
        }
        for (int e = tid; e < 8768; e += 256){
            int o = e / 137, i = e - o*137;
            ws[OFF_WBT + i*64 + o] = Wb[e];
        }
        __syncthreads();
        if (tid < 136){
            int r, c; tri_rc(tid, r, c);
            float sr = s_srt[r], sc = s_srt[c];
            float den = sr - sc;
            bool eq = fabsf(den) < EPSV;
            float er = expf(sr), ec = expf(sc);
            float num = eq ? 0.5f*(er + ec) : (er - ec);
            float dd  = eq ? 1.f : den;
            float scale = (r == c) ? 1.f : SQRT2F;
            ws[OFF_G + tid] = scale * num / dd;
        }
        return;
    }
    float* Bl = sm;                // g*320 + i*20 + t; cof[j] at g*320+(j>>2)*20+16+(j&3)
    const size_t m = (size_t)blockIdx.x * 16 + g;
    const float* xp = x + m * 256;
    v2f b[8]; float nrm = 0.f;
    float* bf = (float*)b;
#pragma unroll
    for (int i = 0; i < 16; ++i){
        float val = xp[i*16 + t];
        bf[i] = val;
        nrm = fmaf(val, val, nrm);
    }
#pragma unroll 1
    for (int sw = 0; sw < NSWEEP_BIG; ++sw)
        if (!jac_sweep<false>(b, b, nrm, t)) break;
    float n2 = 0.f;
#pragma unroll
    for (int i = 0; i < 16; ++i) n2 = fmaf(bf[i], bf[i], n2);
    float lam = sqrtf(n2);
    float w = logf(fmaxf(lam, EPSV));
    float coef = w / n2;            // logm = sum_j coef_j b_j b_j^T
#pragma unroll
    for (int i = 0; i < 16; ++i) Bl[g*320 + i*20 + t] = bf[i];
    Bl[g*320 + (t>>2)*20 + 16 + (t&3)] = coef;   // cof[t] in row-t>>2 padding
    __syncthreads();
    float outv[9];
    float* Lp = L + m * 136;
#pragma unroll
    for (int k = 0; k < 9; ++k){
        int d = t + 16*k;
        float acc = 0.f;
        if (d < 136){
            int r, c; tri_rc(d, r, c);
            const float4* Br = (const float4*)&Bl[g*320 + r*20];
            const float4* Bc = (const float4*)&Bl[g*320 + c*20];
            v2f a2 = {0.f, 0.f};
#pragma unroll
            for (int j4 = 0; j4 < 4; ++j4){
                float4 br = Br[j4], bc = Bc[j4];
                float4 cf = *(const float4*)&Bl[g*320 + j4*20 + 16];
                v2f p1 = pk_mul((v2f){br.x, br.y}, (v2f){cf.x, cf.y});
                a2 = pk_fma(p1, (v2f){bc.x, bc.y}, a2);
                v2f p2 = pk_mul((v2f){br.z, br.w}, (v2f){cf.z, cf.w});
                a2 = pk_fma(p2, (v2f){bc.z, bc.w}, a2);
            }
            acc = a2.x + a2.y;
            Lp[d] = acc;
        }
        outv[k] = acc;
    }
    __syncthreads();
    float* red = sm;                // red[g*144 + d]
#pragma unroll
    for (int k = 0; k < 9; ++k){
        int d = t + 16*k;
        red[g*144 + d] = outv[k];
    }
    __syncthreads();
    if (tid < 136){
        float s = 0.f;
#pragma unroll
        for (int gg = 0; gg < 16; ++gg) s += red[gg*144 + tid];
        mpart[(size_t)blockIdx.x * 136 + tid] = s;
    }
}

// ---------------------------------------------------------------------------
// C: finalize mean from 200 block-partials per n. 3-way c-split (408 threads).
__global__ __launch_bounds__(512) void k_xm_mean(float* __restrict__ ws){
    __shared__ float part[3][136];
    const int n = blockIdx.x;
    const int tid = threadIdx.x;
    const int h = tid / 136;
    const int d = tid - h*136;
    if (tid < 408){
        int c0 = h*67, c1 = (h == 2) ? 200 : (c0 + 67);
        const float* mp = ws + OFF_MPART + (size_t)n * 200 * 136 + d;
        float s = 0.f;
#pragma unroll 4
        for (int c = c0; c < c1; ++c) s += mp[(size_t)c * 136];
        part[h][d] = s;
    }
    __syncthreads();
    if (tid < 136)
        ws[OFF_MEAN + n*136 + tid] =
            ((part[0][tid] + part[1][tid]) + part[2][tid]) * (1.f/3200.f);
}

// ---------------------------------------------------------------------------
// E: blocks 0..511: partial covariance (R13 version: 8x4 tiles, hf*153 split).
//    Blocks 512..543: xm eigendecomp.
__global__ __launch_bounds__(256) void k_cov(float* __restrict__ ws){
    __shared__ __align__(16) float xc[16][136];
    __shared__ __align__(16) float Gl[136];
    __shared__ __align__(16) float Ml[136];
    const int bid = blockIdx.x;
    const int tid = threadIdx.x;
    if (bid >= 512){
        const int n = bid - 512;
        float* smf = &xc[0][0];
        float* Ms  = smf;              // 136
        float* Vl  = smf + 144;        // 16*20
        float* Hl2 = smf + 464;        // 16*20
        if (tid < 136) Ms[tid] = ws[OFF_MEAN + n*136 + tid];
        __syncthreads();
        const int t = tid & 15;
        if (tid < 64){
            v2f b[8], v[8]; float nrm = 0.f;
            float* bf = (float*)b;
            float* vf = (float*)v;
#pragma unroll
            for (int i = 0; i < 16; ++i){
                int r = (i > t) ? i : t, c = (i > t) ? t : i;
                bf[i] = Ms[r*(r+1)/2 + c];
                vf[i] = (i == t) ? 1.f : 0.f;
                nrm = fmaf(bf[i], bf[i], nrm);
            }
#pragma unroll 1
            for (int sw = 0; sw < NSWEEP_SMALL; ++sw)
                if (!jac_sweep<true>(b, v, nrm, t)) break;
            float lam = 0.f;
#pragma unroll
            for (int i = 0; i < 16; ++i) lam = fmaf(vf[i], bf[i], lam);  // signed
            float w = logf(fmaxf(lam, EPSV));
            if (tid < 16){
#pragma unroll
                for (int i = 0; i < 16; ++i){ Vl[i*20 + t] = vf[i]; Hl2[i*20 + t] = w * vf[i]; }
            }
        }
        __syncthreads();
        if (tid < 16){
            for (int k = 0; k < 9; ++k){
                int d = t + 16*k;
                if (d < 136){
                    int r, c; tri_rc(d, r, c);
                    float acc = 0.f;
#pragma unroll
                    for (int j = 0; j < 16; ++j) acc = fmaf(Hl2[r*20 + j], Vl[c*20 + j], acc);
                    float scale = (r == c) ? 1.f : SQRT2F;
                    ws[OFF_XM + n*136 + d] = scale * acc;
                }
            }
        }
        return;
    }
    const int n = bid & 31, c8 = (bid >> 5) & 7, hf = bid >> 8;
    if (tid < 136){
        Gl[tid] = ws[OFF_G + tid];
        Ml[tid] = ws[OFF_MEAN + n*136 + tid];
    }
    int bi = 0, bj = 0; const bool val = (tid < 153);
    if (val){
        int T = hf*153 + tid;
        int bb = (int)floorf((sqrtf(fmaf(4.f, (float)T, 1.f)) - 1.f) * 0.5f);
        while (bb*bb + bb > T) bb--;
        while ((bb+1)*(bb+1) + (bb+1) <= T) bb++;
        bi = bb; bj = T - bb*bb - bb;
    }
    // accumulators as di-pairs: av[p*4+dj] = {a(2p,dj), a(2p+1,dj)}
    v2f av[16];
#pragma unroll
    for (int i = 0; i < 16; ++i) av[i] = (v2f){0.f, 0.f};
    const float* Lbase = ws + OFF_L + (size_t)n * 3200 * 136;
    for (int st = 0; st < 25; ++st){
        __syncthreads();
        int p0 = c8*400 + st*16;
        for (int f = tid; f < 544; f += 256){
            int pp = f / 34, dd = f - pp*34;
            float4 lv = *(const float4*)(Lbase + (size_t)(p0+pp)*136 + dd*4);
            float4 gv = *(const float4*)(&Gl[dd*4]);
            float4 mv = *(const float4*)(&Ml[dd*4]);
            float4 r;
            r.x = (lv.x - mv.x) * gv.x; r.y = (lv.y - mv.y) * gv.y;
            r.z = (lv.z - mv.z) * gv.z; r.w = (lv.w - mv.w) * gv.w;
            *(float4*)(&xc[pp][dd*4]) = r;
        }
        __syncthreads();
        if (val){
#pragma unroll 1
            for (int pp = 0; pp < 16; ++pp){
                const float4 u0 = *(const float4*)(&xc[pp][bi*8]);
                const float4 u1 = *(const float4*)(&xc[pp][bi*8+4]);
                const float4 w4 = *(const float4*)(&xc[pp][bj*4]);
                v2f u01 = {u0.x, u0.y}, u23 = {u0.z, u0.w};
                v2f u45 = {u1.x, u1.y}, u67 = {u1.z, u1.w};
                float wj[4] = {w4.x, w4.y, w4.z, w4.w};
#pragma unroll
                for (int dj = 0; dj < 4; ++dj){
                    v2f wb = {wj[dj], wj[dj]};
                    av[0*4+dj] = pk_fma(u01, wb, av[0*4+dj]);
                    av[1*4+dj] = pk_fma(u23, wb, av[1*4+dj]);
                    av[2*4+dj] = pk_fma(u45, wb, av[2*4+dj]);
                    av[3*4+dj] = pk_fma(u67, wb, av[3*4+dj]);
                }
            }
        }
    }
    if (val){
        float* part = ws + OFF_PART + ((size_t)c8*32 + n)*9316;
#pragma unroll
        for (int p = 0; p < 4; ++p){
#pragma unroll
            for (int h = 0; h < 2; ++h){
                int i = bi*8 + p*2 + h;
#pragma unroll
                for (int dj = 0; dj < 4; ++dj){
                    int j = bj*4 + dj;
                    if (j <= i) part[i*(i+1)/2 + j] = av[p*4+dj][h];
                }
            }
        }
    }
}

// ---------------------------------------------------------------------------
// F: sum partials -> cov -> single-barrier Cholesky. Updaters compute
//    cis = T[i][k]*rinv themselves (same bits as the old ck[]); the scaled
//    factor is materialized at write-out with dg/rc2 (identical exprs).
#define TST 141   // T row stride: 141 mod 32 = 13, gcd(13,32)=1 -> conflict-free cols
__global__ __launch_bounds__(512) void k_chol(float* __restrict__ ws){
    __shared__ float T[136*TST];    // 76.7 KB (raw columns; scaled at writeout)
    __shared__ float dg[136];       // sqrtf(diag)
    __shared__ float rc2[136];      // 1/sqrtf(diag) == in-loop rinv expr
    const int n = blockIdx.x;
    const int tid = threadIdx.x;
    // stage cov (tri-packed partials -> full lower)
    for (int e = tid; e < 9316; e += 512){
        float s = 0.f;
#pragma unroll
        for (int c = 0; c < 8; ++c) s += ws[OFF_PART + ((size_t)c*32 + n)*9316 + e];
        int r, cc2; tri_rc(e, r, cc2);
        T[r*TST + cc2] = s * (1.f/3199.f);
    }
    __syncthreads();
    // right-looking Cholesky, ONE barrier per k. Column k is read-only raw
    // during iteration k; trailing writes are to columns >= k+1 (disjoint).
    for (int k = 0; k < 135; ++k){
        float dkk = sqrtf(T[k*TST + k]);
        float rinv = 1.f / dkk;
        const int m = 135 - k;
        const int cnt = m*(m+1)/2;
        const int Lc = (cnt + 511) >> 9;
        int e0 = tid * Lc, e1 = e0 + Lc; if (e1 > cnt) e1 = cnt;
        if (e0 < e1){
            float A = 2.f*m + 1.f;
            int jp = (int)floorf((A - sqrtf(fmaf(A, A, -8.f*e0))) * 0.5f);
            if (jp < 0) jp = 0;
            while (jp > 0 && jp*m - jp*(jp-1)/2 > e0) jp--;
            while ((jp+1)*m - (jp+1)*jp/2 <= e0) jp++;
            int ip = jp + (e0 - (jp*m - jp*(jp-1)/2));
            int i = k+1+ip, j = k+1+jp;
            int ix = i*TST + j;
            int e = e0;
            while (e < e1){
                int nb = e1 - e; if (nb > 8) nb = 8;
                int   ixs[8]; float cis[8], cjs[8], tv[8];
#pragma unroll
                for (int b2 = 0; b2 < 8; ++b2){
                    if (b2 < nb){
                        ixs[b2] = ix;
                        cis[b2] = T[i*TST + k] * rinv;   // == old ck[i]
                        cjs[b2] = T[j*TST + k] * rinv;   // == old ck[j]
                        i++; ix += TST;
                        if (i == 136){ j++; i = j; ix = i*TST + j; }
                    }
                }
#pragma unroll
                for (int b2 = 0; b2 < 8; ++b2) if (b2 < nb) tv[b2] = T[ixs[b2]];
#pragma unroll
                for (int b2 = 0; b2 < 8; ++b2) if (b2 < nb) tv[b2] = fmaf(-cis[b2], cjs[b2], tv[b2]);
#pragma unroll
                for (int b2 = 0; b2 < 8; ++b2) if (b2 < nb) T[ixs[b2]] = tv[b2];
                e += nb;
            }
        }
        __syncthreads();
    }
    // diag sqrt + per-column scale (identical expressions to in-loop values)
    if (tid < 136){
        float d = sqrtf(T[tid*TST + tid]);
        dg[tid] = d;
        rc2[tid] = 1.f / d;
    }
    __syncthreads();
    if (tid == 0){
        float tr = 1.f;
        for (int kk = 0; kk < 136; ++kk) tr += dg[kk];
        ws[OFF_TR + n*2]     = tr;
        ws[OFF_TR + n*2 + 1] = 1.f / tr;
    }
    // write tri-packed scaled factor
    for (int e = tid; e < 9316; e += 512){
        int r, c; tri_rc(e, r, c);
        float v = (r == c) ? dg[c] : T[r*TST + c] * rc2[c];
        ws[OFF_CT + (size_t)n*9320 + e] = v;
    }
}

// ---------------------------------------------------------------------------
// F2: fused Tout+bimap, column-split, vector-friendly layouts. Block (n, qs)
//     computes Tout columns q = qs*8..qs*8+7 for all rows i, then the bimap
//     slice out[n][all o][those q]. wt8/tt8 laid out [ql*140 + j] so both the
//     Tout dot (stride-1, compiler-merged b128) and the bimap dot (explicit
//     float4 single-accumulator ascending chain == old k_bimap order) are
//     vectorized. Bit-identical to the R13 k_tout/k_bimap pair.
__global__ __launch_bounds__(512) void k_tail(float* __restrict__ ws,
                                              const float* __restrict__ Wb,
                                              float* __restrict__ out){
    __shared__ __align__(16) float ct[9320];   // tri factor; then Wb rows @140
    __shared__ __align__(16) float wt8[1120];  // [ql*140 + j], j<137
    __shared__ __align__(16) float tt8[1120];  // [ql*140 + i], i<137
    __shared__ float xs[137];
    const int bid = blockIdx.x;
    const int n = bid >> 3, qs = bid & 7;
    const int tid = threadIdx.x;
    const float* ctg = ws + OFF_CT + (size_t)n * 9320;
    for (int e = tid; e < 9316; e += 512) ct[e] = ctg[e];
    for (int e = tid; e < 1096; e += 512){
        int ql = e / 137, j = e - ql*137;
        wt8[ql*140 + j] = ws[OFF_WBT + j*64 + qs*8 + ql];
    }
    if (tid < 137) xs[tid] = (tid < 136) ? ws[OFF_XM + n*136 + tid] : 1.f;
    __syncthreads();
    const float tr  = ws[OFF_TR + n*2];
    const float itr = ws[OFF_TR + n*2 + 1];
    const float c6 = tr * 1e-6f;
    for (int task = tid; task < 1096; task += 512){
        int i = task >> 3, ql = task & 7;
        const float* wq = wt8 + ql*140;
        if (i < 136){
            const float* cr = ct + i*(i+1)/2;
            float acc = 0.f;
            for (int j = 0; j <= i; ++j) acc = fmaf(cr[j], wq[j], acc);
            tt8[ql*140 + i] = fmaf(c6, wq[i], itr * acc);
        } else {
            float acc = wq[136];               // out[D][D] = 1 term first
            for (int j = 0; j < 136; ++j) acc = fmaf(xs[j], wq[j], acc);
            tt8[ql*140 + 136] = fmaf(c6, wq[136], itr * acc);
        }
    }
    __syncthreads();
    // ct dead -> reuse for Wb rows at aligned stride 140
    for (int e = tid; e < 8768; e += 512){
        int o = e / 137, i = e - o*137;
        ct[o*140 + i] = Wb[e];
    }
    __syncthreads();
    const int o = tid >> 3, ql = tid & 7;
    const float* wr = ct + o*140;
    const float* tq = tt8 + ql*140;
    float acc = 0.f;
#pragma unroll 1
    for (int i = 0; i < 136; i += 4){
        float4 tv = *(const float4*)(tq + i);
        float4 wv = *(const float4*)(wr + i);
        acc = fmaf(tv.x, wv.x, acc); acc = fmaf(tv.y, wv.y, acc);
        acc = fmaf(tv.z, wv.z, acc); acc = fmaf(tv.w, wv.w, acc);
    }
    acc = fmaf(tq[136], wr[136], acc);
    out[(size_t)n*4096 + o*64 + qs*8 + ql] = acc;
}

// ---------------------------------------------------------------------------
extern "C" void kernel_launch(void* const* d_in, const int* in_sizes, int n_in,
                              void* d_out, int out_size, void* d_ws, size_t ws_size,
                              hipStream_t stream){
    const float* x   = (const float*)d_in[0];
    const float* W   = (const float*)d_in[1];
    const float* Wb  = (const float*)d_in[2];
    float* out = (float*)d_out;
    float* ws  = (float*)d_ws;

    k_logm   <<<6401, 256, 0, stream>>>(x, ws + OFF_L, ws + OFF_MPART, W, Wb, ws);
    k_xm_mean<<<  32, 512, 0, stream>>>(ws);
    k_cov    <<< 544, 256, 0, stream>>>(ws);
    k_chol   <<<  32, 512, 0, stream>>>(ws);
    k_tail   <<< 256, 512, 0, stream>>>(ws, Wb, out);
}

// Round 10
// 578.465 us; speedup vs baseline: 1.3004x; 1.2307x over previous
//
#include <hip/hip_runtime.h>
#include <math.h>

// ---------------------------------------------------------------------------
// RiemannianPooling: logm(eigh) -> mean -> diff_exp -> cov -> cholesky -> bimap
// N=32, M*T*V=3200, C=16, D=136, out 32x64x64 fp32.
// R17: single change vs R16 — k_chol panel-8 blocked Cholesky (BIT-EXACT):
//  rank-8 trailing update touches each element once per 8 columns (11 LDS b32
//  per 8 fmas vs 32) -> ~2.7x DS cut on the 32-CU-bound kernel. Each element
//  still receives fmas in ascending-k order (sequential chain); panel columns
//  factored with identical raw*rinv / sqrtf / 1.f/dd expressions; diag kept
//  raw in T (dg[] holds sqrt) to avoid the broadcast-diag write race.
//  Everything else byte-frozen from R16 (712us, absmax 1.525879e-05).
// ---------------------------------------------------------------------------

#define EPSV 1e-4f
#define NSWEEP_BIG 6
#define NSWEEP_SMALL 10
#define SQRT2F 1.41421356237309515f

// workspace layout (float offsets) — total 66.5 MB
#define OFF_G      0            // 136
#define OFF_WBT    160          // 137*64 = 8768
#define OFF_MEAN   8960         // 32*136
#define OFF_XM     13312        // 32*136
#define OFF_TR     17664        // 32*2 (tr, 1/tr)
#define OFF_CT     17792        // 32*9320 tri-packed cholesky factor (ends 316032)
#define OFF_MPART  320000       // 6400*136 (aliases head of PART)
#define OFF_PART   320000       // 8*32*9316 (written after MPART consumed)
#define OFF_L      2704896      // 102400*136

typedef float v2f __attribute__((ext_vector_type(2)));

__device__ __forceinline__ float rcp_f(float x){ return __builtin_amdgcn_rcpf(x); }
__device__ __forceinline__ float rsq_f(float x){ return __builtin_amdgcn_rsqf(x); }

// Packed fp32 (VOP3P). Only profitable where operands already flow as pairs
// (R11 post-mortem: scalar-consumed halves force v_mov marshaling).
__device__ __forceinline__ v2f pk_fma(v2f a, v2f b, v2f c){
    v2f d;
    asm("v_pk_fma_f32 %0, %1, %2, %3" : "=v"(d) : "v"(a), "v"(b), "v"(c));
    return d;
}
__device__ __forceinline__ v2f pk_mul(v2f a, v2f b){
    v2f d;
    asm("v_pk_mul_f32 %0, %1, %2" : "=v"(d) : "v"(a), "v"(b));
    return d;
}

// XOR within 16-lane rows via single DPP (VALU pipe).
template<int R>
__device__ __forceinline__ float xl(float x){
    int s = __float_as_int(x);
    if constexpr (R == 1){
        return __int_as_float(__builtin_amdgcn_update_dpp(s, s, 0xB1, 0xF, 0xF, false));
    } else if constexpr (R == 2){
        return __int_as_float(__builtin_amdgcn_update_dpp(s, s, 0x4E, 0xF, 0xF, false));
    } else if constexpr (R == 3){
        return __int_as_float(__builtin_amdgcn_update_dpp(s, s, 0x1B, 0xF, 0xF, false));
    } else if constexpr (R == 7){
        return __int_as_float(__builtin_amdgcn_update_dpp(s, s, 0x141, 0xF, 0xF, false));
    } else if constexpr (R == 8){
        return __int_as_float(__builtin_amdgcn_update_dpp(s, s, 0x128, 0xF, 0xF, false));
    } else {  // R == 15
        return __int_as_float(__builtin_amdgcn_update_dpp(s, s, 0x140, 0xF, 0xF, false));
    }
}

// Pipe split: masks {4,5,6,9..14} -> DS crossbar; {1,2,3,7,8,15} on VALU DPP.
// (R9 post-mortem: DO NOT convert the DS ones to 2-DPP compositions — at
// high VALU pressure with multi-wave occupancy the crossbar ops are free, and
// the composition adds ~30% VALU issue -> 375->540us regression.)
template<int R>
__device__ __forceinline__ float shuf(float x){
    if constexpr ((R >= 4 && R <= 6) || R >= 9){
        constexpr int IMM = (R << 10) | 0x1F;   // BitMode: xor=R, and=0x1F
        return __int_as_float(__builtin_amdgcn_ds_swizzle(__float_as_int(x), IMM));
    } else {
        return xl<R>(x);
    }
}

// decode linear lower-tri index d -> (r,c), d = r(r+1)/2 + c
__device__ __forceinline__ void tri_rc(int d, int &r, int &c){
    int rr = (int)floorf((sqrtf(fmaf(8.f, (float)d, 1.f)) - 1.f) * 0.5f);
    if (rr*(rr+1)/2 > d) rr--;
    if ((rr+1)*(rr+2)/2 <= d) rr++;
    r = rr; c = d - rr*(rr+1)/2;
}

// One XOR-tournament round of one-sided Jacobi. 16 lanes per matrix.
// Rotation from (d = nrm-pn, gam) with 2 rsq; per-lane sign automatic
// (d antisymmetric across the pair); wave-uniform noise-floor skip.
// Returns nonzero iff a rotation was applied (wave-uniform).
template<int R, bool WV>
__device__ __forceinline__ int jac_round(v2f* b, v2f* v, float &nrm, int t){
    v2f pc[8];
#pragma unroll
    for (int i = 0; i < 8; ++i){ pc[i].x = shuf<R>(b[i].x); pc[i].y = shuf<R>(b[i].y); }
    float pn = shuf<R>(nrm);
    // Gram dot: 8 pk_fma in 2 chains (4-deep) instead of 16 scalar fma.
    v2f ga = pk_mul(b[0], pc[0]);
    v2f gb = pk_mul(b[1], pc[1]);
    ga = pk_fma(b[2], pc[2], ga); gb = pk_fma(b[3], pc[3], gb);
    ga = pk_fma(b[4], pc[4], ga); gb = pk_fma(b[5], pc[5], gb);
    ga = pk_fma(b[6], pc[6], ga); gb = pk_fma(b[7], pc[7], gb);
    float gam = (ga.x + gb.x) + (ga.y + gb.y);
    // adaptive skip: |gam| <= 4e-7*sqrt(nrm*pn) is update-noise level; if every
    // pair in the wave (4 matrices) is there, the rotations are identity-level.
    bool live = (gam*gam > 1.6e-13f * (nrm * pn));
    int lv = __any((int)live);
    if (lv){
        constexpr int HB = (R & 8) ? 8 : ((R & 4) ? 4 : ((R & 2) ? 2 : 1));
        const bool isp = ((t & HB) == 0);
        // antisymmetric tie-break: if nrm==pn exactly, d still has opposite
        // signs in the two lanes of a pair.
        float d = (nrm - pn) + (isp ? 1e-30f : -1e-30f);
        float g22 = gam + gam;
        float nrr = fmaf(g22, g22, d*d);
        float inv_r = rsq_f(nrr);                      // 1/sqrt(d^2+4g^2)
        float c2 = fmaf(0.5f*fabsf(d), inv_r, 0.5f);   // cos^2(theta), >= 0.5
        float cinv = rsq_f(c2);
        float smag = fabsf(gam) * inv_r * cinv;        // |sin(theta)|
        int sgn = (__float_as_int(gam) ^ __float_as_int(d)) & 0x80000000;
        bool zn = (nrr == 0.f);                        // fully degenerate pair
        float c = zn ? 1.f : c2 * cinv;
        float s = zn ? 0.f : __int_as_float(__float_as_int(smag) | sgn);
        v2f cv = {c, c};
        v2f sv = {s, s};
#pragma unroll
        for (int i = 0; i < 8; ++i) b[i] = pk_fma(pc[i], sv, pk_mul(b[i], cv));
        if (WV){
            v2f pv[8];
#pragma unroll
            for (int i = 0; i < 8; ++i){ pv[i].x = shuf<R>(v[i].x); pv[i].y = shuf<R>(v[i].y); }
#pragma unroll
            for (int i = 0; i < 8; ++i) v[i] = pk_fma(pv[i], sv, pk_mul(v[i], cv));
        }
        nrm = fmaf(s * cinv, gam, nrm);                // alpha' = alpha + t*gam
    }
    return lv;
}

// Returns nonzero iff any round applied a rotation. If zero, b (and v) are
// bit-identical to sweep entry -> all later sweeps are no-ops (exact break).
template<bool WV>
__device__ __forceinline__ int jac_sweep(v2f* b, v2f* v, float &nrm, int t){
    int lv = 0;
    lv |= jac_round< 4,WV>(b,v,nrm,t); lv |= jac_round< 1,WV>(b,v,nrm,t);
    lv |= jac_round< 5,WV>(b,v,nrm,t); lv |= jac_round< 2,WV>(b,v,nrm,t);
    lv |= jac_round< 6,WV>(b,v,nrm,t); lv |= jac_round< 3,WV>(b,v,nrm,t);
    lv |= jac_round< 9,WV>(b,v,nrm,t); lv |= jac_round< 7,WV>(b,v,nrm,t);
    lv |= jac_round<10,WV>(b,v,nrm,t); lv |= jac_round< 8,WV>(b,v,nrm,t);
    lv |= jac_round<11,WV>(b,v,nrm,t); lv |= jac_round<15,WV>(b,v,nrm,t);
    lv |= jac_round<12,WV>(b,v,nrm,t); lv |= jac_round<13,WV>(b,v,nrm,t);
    lv |= jac_round<14,WV>(b,v,nrm,t);
    return lv;
}

// ---------------------------------------------------------------------------
// B: per-matrix eigh + logm lower triangle + per-block mean partials. (FROZEN)
__global__ __launch_bounds__(256) void k_logm(const float* __restrict__ x,
                                              float* __restrict__ L,
                                              float* __restrict__ mpart,
                                              const float* __restrict__ W,
                                              const float* __restrict__ Wb,
                                              float* __restrict__ ws){
    __shared__ float sm[5120];     // Bl[16][16 rows x 20] with cof in padding
                                   // (20480 B = exactly 160KB/8 -> 8 blocks/CU)
    const int tid = threadIdx.x;
    const int t = tid & 15;
    const int g = tid >> 4;
    if (blockIdx.x == 6400){
        // ---- prep: s = svd(W_sym) desc -> G; WbT transpose ----
        float* sigv  = sm;          // 16
        float* s_srt = sm + 16;     // 16
        if (tid < 64){
            v2f b[8]; float nrm = 0.f;
            float* bf = (float*)b;
#pragma unroll
            for (int i = 0; i < 16; ++i){
                float val = 0.5f * (W[i*16 + t] + W[t*16 + i]);
                bf[i] = val;
                nrm = fmaf(val, val, nrm);
            }
#pragma unroll 1
            for (int sw = 0; sw < NSWEEP_SMALL; ++sw)
                if (!jac_sweep<false>(b, b, nrm, t)) break;
            float n2 = 0.f;
#pragma unroll
            for (int i = 0; i < 16; ++i) n2 = fmaf(bf[i], bf[i], n2);
            float sig = sqrtf(n2);
            if (tid < 16) sigv[t] = sig;
        }
        __syncthreads();
        if (tid < 16){
            float sig = sigv[t];
            int rank = 0;
#pragma unroll
            for (int u = 0; u < 16; ++u){
                float su = sigv[u];
                rank += (su > sig || (su == sig && u < t)) ? 1 : 0;
            }
            s_srt[rank] = sig;   // descending, matches jnp.linalg.svd order
        }
        for (int e = tid; e < 8768; e += 256){
            int o = e / 137, i = e - o*137;
            ws[OFF_WBT + i*64 + o] = Wb[e];
        }
        __syncthreads();
        if (tid < 136){
            int r, c; tri_rc(tid, r, c);
            float sr = s_srt[r], sc = s_srt[c];
            float den = sr - sc;
            bool eq = fabsf(den) < EPSV;
            float er = expf(sr), ec = expf(sc);
            float num = eq ? 0.5f*(er + ec) : (er - ec);
            float dd  = eq ? 1.f : den;
            float scale = (r == c) ? 1.f : SQRT2F;
            ws[OFF_G + tid] = scale * num / dd;
        }
        return;
    }
    float* Bl = sm;                // g*320 + i*20 + t; cof[j] at g*320+(j>>2)*20+16+(j&3)
    const size_t m = (size_t)blockIdx.x * 16 + g;
    const float* xp = x + m * 256;
    v2f b[8]; float nrm = 0.f;
    float* bf = (float*)b;
#pragma unroll
    for (int i = 0; i < 16; ++i){
        float val = xp[i*16 + t];
        bf[i] = val;
        nrm = fmaf(val, val, nrm);
    }
#pragma unroll 1
    for (int sw = 0; sw < NSWEEP_BIG; ++sw)
        if (!jac_sweep<false>(b, b, nrm, t)) break;
    float n2 = 0.f;
#pragma unroll
    for (int i = 0; i < 16; ++i) n2 = fmaf(bf[i], bf[i], n2);
    float lam = sqrtf(n2);
    float w = logf(fmaxf(lam, EPSV));
    float coef = w / n2;            // logm = sum_j coef_j b_j b_j^T
#pragma unroll
    for (int i = 0; i < 16; ++i) Bl[g*320 + i*20 + t] = bf[i];
    Bl[g*320 + (t>>2)*20 + 16 + (t&3)] = coef;   // cof[t] in row-t>>2 padding
    __syncthreads();
    float outv[9];
    float* Lp = L + m * 136;
#pragma unroll
    for (int k = 0; k < 9; ++k){
        int d = t + 16*k;
        float acc = 0.f;
        if (d < 136){
            int r, c; tri_rc(d, r, c);
            const float4* Br = (const float4*)&Bl[g*320 + r*20];
            const float4* Bc = (const float4*)&Bl[g*320 + c*20];
            v2f a2 = {0.f, 0.f};
#pragma unroll
            for (int j4 = 0; j4 < 4; ++j4){
                float4 br = Br[j4], bc = Bc[j4];
                float4 cf = *(const float4*)&Bl[g*320 + j4*20 + 16];
                v2f p1 = pk_mul((v2f){br.x, br.y}, (v2f){cf.x, cf.y});
                a2 = pk_fma(p1, (v2f){bc.x, bc.y}, a2);
                v2f p2 = pk_mul((v2f){br.z, br.w}, (v2f){cf.z, cf.w});
                a2 = pk_fma(p2, (v2f){bc.z, bc.w}, a2);
            }
            acc = a2.x + a2.y;
            Lp[d] = acc;
        }
        outv[k] = acc;
    }
    __syncthreads();
    float* red = sm;                // red[g*144 + d]
#pragma unroll
    for (int k = 0; k < 9; ++k){
        int d = t + 16*k;
        red[g*144 + d] = outv[k];
    }
    __syncthreads();
    if (tid < 136){
        float s = 0.f;
#pragma unroll
        for (int gg = 0; gg < 16; ++gg) s += red[gg*144 + tid];
        mpart[(size_t)blockIdx.x * 136 + tid] = s;
    }
}

// ---------------------------------------------------------------------------
// C: finalize mean from 200 block-partials per n. 3-way c-split (408 threads).
__global__ __launch_bounds__(512) void k_xm_mean(float* __restrict__ ws){
    __shared__ float part[3][136];
    const int n = blockIdx.x;
    const int tid = threadIdx.x;
    const int h = tid / 136;
    const int d = tid - h*136;
    if (tid < 408){
        int c0 = h*67, c1 = (h == 2) ? 200 : (c0 + 67);
        const float* mp = ws + OFF_MPART + (size_t)n * 200 * 136 + d;
        float s = 0.f;
#pragma unroll 4
        for (int c = c0; c < c1; ++c) s += mp[(size_t)c * 136];
        part[h][d] = s;
    }
    __syncthreads();
    if (tid < 136)
        ws[OFF_MEAN + n*136 + tid] =
            ((part[0][tid] + part[1][tid]) + part[2][tid]) * (1.f/3200.f);
}

// ---------------------------------------------------------------------------
// E: blocks 0..511: partial covariance (R13 version: 8x4 tiles, hf*153 split).
//    Blocks 512..543: xm eigendecomp.
__global__ __launch_bounds__(256) void k_cov(float* __restrict__ ws){
    __shared__ __align__(16) float xc[16][136];
    __shared__ __align__(16) float Gl[136];
    __shared__ __align__(16) float Ml[136];
    const int bid = blockIdx.x;
    const int tid = threadIdx.x;
    if (bid >= 512){
        const int n = bid - 512;
        float* smf = &xc[0][0];
        float* Ms  = smf;              // 136
        float* Vl  = smf + 144;        // 16*20
        float* Hl2 = smf + 464;        // 16*20
        if (tid < 136) Ms[tid] = ws[OFF_MEAN + n*136 + tid];
        __syncthreads();
        const int t = tid & 15;
        if (tid < 64){
            v2f b[8], v[8]; float nrm = 0.f;
            float* bf = (float*)b;
            float* vf = (float*)v;
#pragma unroll
            for (int i = 0; i < 16; ++i){
                int r = (i > t) ? i : t, c = (i > t) ? t : i;
                bf[i] = Ms[r*(r+1)/2 + c];
                vf[i] = (i == t) ? 1.f : 0.f;
                nrm = fmaf(bf[i], bf[i], nrm);
            }
#pragma unroll 1
            for (int sw = 0; sw < NSWEEP_SMALL; ++sw)
                if (!jac_sweep<true>(b, v, nrm, t)) break;
            float lam = 0.f;
#pragma unroll
            for (int i = 0; i < 16; ++i) lam = fmaf(vf[i], bf[i], lam);  // signed
            float w = logf(fmaxf(lam, EPSV));
            if (tid < 16){
#pragma unroll
                for (int i = 0; i < 16; ++i){ Vl[i*20 + t] = vf[i]; Hl2[i*20 + t] = w * vf[i]; }
            }
        }
        __syncthreads();
        if (tid < 16){
            for (int k = 0; k < 9; ++k){
                int d = t + 16*k;
                if (d < 136){
                    int r, c; tri_rc(d, r, c);
                    float acc = 0.f;
#pragma unroll
                    for (int j = 0; j < 16; ++j) acc = fmaf(Hl2[r*20 + j], Vl[c*20 + j], acc);
                    float scale = (r == c) ? 1.f : SQRT2F;
                    ws[OFF_XM + n*136 + d] = scale * acc;
                }
            }
        }
        return;
    }
    const int n = bid & 31, c8 = (bid >> 5) & 7, hf = bid >> 8;
    if (tid < 136){
        Gl[tid] = ws[OFF_G + tid];
        Ml[tid] = ws[OFF_MEAN + n*136 + tid];
    }
    int bi = 0, bj = 0; const bool val = (tid < 153);
    if (val){
        int T = hf*153 + tid;
        int bb = (int)floorf((sqrtf(fmaf(4.f, (float)T, 1.f)) - 1.f) * 0.5f);
        while (bb*bb + bb > T) bb--;
        while ((bb+1)*(bb+1) + (bb+1) <= T) bb++;
        bi = bb; bj = T - bb*bb - bb;
    }
    // accumulators as di-pairs: av[p*4+dj] = {a(2p,dj), a(2p+1,dj)}
    v2f av[16];
#pragma unroll
    for (int i = 0; i < 16; ++i) av[i] = (v2f){0.f, 0.f};
    const float* Lbase = ws + OFF_L + (size_t)n * 3200 * 136;
    for (int st = 0; st < 25; ++st){
        __syncthreads();
        int p0 = c8*400 + st*16;
        for (int f = tid; f < 544; f += 256){
            int pp = f / 34, dd = f - pp*34;
            float4 lv = *(const float4*)(Lbase + (size_t)(p0+pp)*136 + dd*4);
            float4 gv = *(const float4*)(&Gl[dd*4]);
            float4 mv = *(const float4*)(&Ml[dd*4]);
            float4 r;
            r.x = (lv.x - mv.x) * gv.x; r.y = (lv.y - mv.y) * gv.y;
            r.z = (lv.z - mv.z) * gv.z; r.w = (lv.w - mv.w) * gv.w;
            *(float4*)(&xc[pp][dd*4]) = r;
        }
        __syncthreads();
        if (val){
#pragma unroll 1
            for (int pp = 0; pp < 16; ++pp){
                const float4 u0 = *(const float4*)(&xc[pp][bi*8]);
                const float4 u1 = *(const float4*)(&xc[pp][bi*8+4]);
                const float4 w4 = *(const float4*)(&xc[pp][bj*4]);
                v2f u01 = {u0.x, u0.y}, u23 = {u0.z, u0.w};
                v2f u45 = {u1.x, u1.y}, u67 = {u1.z, u1.w};
                float wj[4] = {w4.x, w4.y, w4.z, w4.w};
#pragma unroll
                for (int dj = 0; dj < 4; ++dj){
                    v2f wb = {wj[dj], wj[dj]};
                    av[0*4+dj] = pk_fma(u01, wb, av[0*4+dj]);
                    av[1*4+dj] = pk_fma(u23, wb, av[1*4+dj]);
                    av[2*4+dj] = pk_fma(u45, wb, av[2*4+dj]);
                    av[3*4+dj] = pk_fma(u67, wb, av[3*4+dj]);
                }
            }
        }
    }
    if (val){
        float* part = ws + OFF_PART + ((size_t)c8*32 + n)*9316;
#pragma unroll
        for (int p = 0; p < 4; ++p){
#pragma unroll
            for (int h = 0; h < 2; ++h){
                int i = bi*8 + p*2 + h;
#pragma unroll
                for (int dj = 0; dj < 4; ++dj){
                    int j = bj*4 + dj;
                    if (j <= i) part[i*(i+1)/2 + j] = av[p*4+dj][h];
                }
            }
        }
    }
}

// ---------------------------------------------------------------------------
// F: sum partials -> cov -> panel-8 blocked Cholesky (bit-exact).
//    Phase A factors the 8 panel columns (scaled off-diag into T, sqrt diag
//    into dg; T diag stays raw). Phase B applies a rank-8 trailing update:
//    each element gets its 8 fmas in ascending-k order (== rank-1 sequence).
#define TST 141   // T row stride: 141 mod 32 = 13, gcd(13,32)=1 -> conflict-free cols
__global__ __launch_bounds__(512) void k_chol(float* __restrict__ ws){
    __shared__ float T[136*TST];    // 76.7 KB
    __shared__ float dg[136];       // sqrtf(diag) per column
    const int n = blockIdx.x;
    const int tid = threadIdx.x;
    // stage cov (tri-packed partials -> full lower)
    for (int e = tid; e < 9316; e += 512){
        float s = 0.f;
#pragma unroll
        for (int c = 0; c < 8; ++c) s += ws[OFF_PART + ((size_t)c*32 + n)*9316 + e];
        int r, cc2; tri_rc(e, r, cc2);
        T[r*TST + cc2] = s * (1.f/3199.f);
    }
    __syncthreads();
    for (int p = 0; p < 17; ++p){
        const int kb = p*8;
        // phase A: factor panel columns. Every thread redundantly computes the
        // raw diag (broadcast reads) -> no barrier between diag and scale.
        for (int c = 0; c < 8; ++c){
            const int k = kb + c;
            float rkk = T[k*TST + k];                  // raw diag (never overwritten)
            for (int c2 = kb; c2 < k; ++c2){
                float v = T[k*TST + c2];
                rkk = fmaf(-v, v, rkk);                // ascending k' order
            }
            float dd = sqrtf(rkk);
            float rinv = 1.f / dd;
            int i = k + 1 + tid;
            if (i <= 135){
                float raw = T[i*TST + k];
                for (int c2 = kb; c2 < k; ++c2)
                    raw = fmaf(-T[i*TST + c2], T[k*TST + c2], raw);
                T[i*TST + k] = raw * rinv;             // same expr as rank-1 ver
            }
            if (tid == 0) dg[k] = dd;
            __syncthreads();
        }
        // phase B: rank-8 trailing update, row-major enumeration (tv reads
        // contiguous; cjs stride TST -> bank +13 conflict-free).
        const int kb2 = kb + 8;
        const int m = 136 - kb2;
        if (m > 0){
            const int cnt = m*(m+1)/2;
            const int Lc = (cnt + 511) >> 9;
            int e0 = tid*Lc, e1 = e0 + Lc; if (e1 > cnt) e1 = cnt;
            if (e0 < e1){
                int r, cj; tri_rc(e0, r, cj);
                int i = kb2 + r, j = kb2 + cj;
                float ci[8];
#pragma unroll
                for (int c = 0; c < 8; ++c) ci[c] = T[i*TST + kb + c];
                for (int e = e0; e < e1; ++e){
                    float tv = T[i*TST + j];
#pragma unroll
                    for (int c = 0; c < 8; ++c)
                        tv = fmaf(-ci[c], T[j*TST + kb + c], tv);  // asc k order
                    T[i*TST + j] = tv;
                    ++j;
                    if (j > i && e + 1 < e1){
                        ++i; j = kb2;
#pragma unroll
                        for (int c = 0; c < 8; ++c) ci[c] = T[i*TST + kb + c];
                    }
                }
            }
        }
        __syncthreads();
    }
    if (tid == 0){
        float tr = 1.f;
        for (int kk = 0; kk < 136; ++kk) tr += dg[kk];
        ws[OFF_TR + n*2]     = tr;
        ws[OFF_TR + n*2 + 1] = 1.f / tr;
    }
    // write tri-packed scaled factor (off-diag already scaled in T)
    for (int e = tid; e < 9316; e += 512){
        int r, c; tri_rc(e, r, c);
        float v = (r == c) ? dg[c] : T[r*TST + c];
        ws[OFF_CT + (size_t)n*9320 + e] = v;
    }
}

// ---------------------------------------------------------------------------
// F2: fused Tout+bimap, column-split, vector-friendly layouts. Block (n, qs)
//     computes Tout columns q = qs*8..qs*8+7 for all rows i, then the bimap
//     slice out[n][all o][those q]. wt8/tt8 laid out [ql*140 + j] so both the
//     Tout dot (stride-1, compiler-merged b128) and the bimap dot (explicit
//     float4 single-accumulator ascending chain == old k_bimap order) are
//     vectorized. Bit-identical to the R13 k_tout/k_bimap pair.
__global__ __launch_bounds__(512) void k_tail(float* __restrict__ ws,
                                              const float* __restrict__ Wb,
                                              float* __restrict__ out){
    __shared__ __align__(16) float ct[9320];   // tri factor; then Wb rows @140
    __shared__ __align__(16) float wt8[1120];  // [ql*140 + j], j<137
    __shared__ __align__(16) float tt8[1120];  // [ql*140 + i], i<137
    __shared__ float xs[137];
    const int bid = blockIdx.x;
    const int n = bid >> 3, qs = bid & 7;
    const int tid = threadIdx.x;
    const float* ctg = ws + OFF_CT + (size_t)n * 9320;
    for (int e = tid; e < 9316; e += 512) ct[e] = ctg[e];
    for (int e = tid; e < 1096; e += 512){
        int ql = e / 137, j = e - ql*137;
        wt8[ql*140 + j] = ws[OFF_WBT + j*64 + qs*8 + ql];
    }
    if (tid < 137) xs[tid] = (tid < 136) ? ws[OFF_XM + n*136 + tid] : 1.f;
    __syncthreads();
    const float tr  = ws[OFF_TR + n*2];
    const float itr = ws[OFF_TR + n*2 + 1];
    const float c6 = tr * 1e-6f;
    for (int task = tid; task < 1096; task += 512){
        int i = task >> 3, ql = task & 7;
        const float* wq = wt8 + ql*140;
        if (i < 136){
            const float* cr = ct + i*(i+1)/2;
            float acc = 0.f;
            for (int j = 0; j <= i; ++j) acc = fmaf(cr[j], wq[j], acc);
            tt8[ql*140 + i] = fmaf(c6, wq[i], itr * acc);
        } else {
            float acc = wq[136];               // out[D][D] = 1 term first
            for (int j = 0; j < 136; ++j) acc = fmaf(xs[j], wq[j], acc);
            tt8[ql*140 + 136] = fmaf(c6, wq[136], itr * acc);
        }
    }
    __syncthreads();
    // ct dead -> reuse for Wb rows at aligned stride 140
    for (int e = tid; e < 8768; e += 512){
        int o = e / 137, i = e - o*137;
        ct[o*140 + i] = Wb[e];
    }
    __syncthreads();
    const int o = tid >> 3, ql = tid & 7;
    const float* wr = ct + o*140;
    const float* tq = tt8 + ql*140;
    float acc = 0.f;
#pragma unroll 1
    for (int i = 0; i < 136; i += 4){
        float4 tv = *(const float4*)(tq + i);
        float4 wv = *(const float4*)(wr + i);
        acc = fmaf(tv.x, wv.x, acc); acc = fmaf(tv.y, wv.y, acc);
        acc = fmaf(tv.z, wv.z, acc); acc = fmaf(tv.w, wv.w, acc);
    }
    acc = fmaf(tq[136], wr[136], acc);
    out[(size_t)n*4096 + o*64 + qs*8 + ql] = acc;
}

// ---------------------------------------------------------------------------
extern "C" void kernel_launch(void* const* d_in, const int* in_sizes, int n_in,
                              void* d_out, int out_size, void* d_ws, size_t ws_size,
                              hipStream_t stream){
    const float* x   = (const float*)d_in[0];
    const float* W   = (const float*)d_in[1];
    const float* Wb  = (const float*)d_in[2];
    float* out = (float*)d_out;
    float* ws  = (float*)d_ws;

    k_logm   <<<6401, 256, 0, stream>>>(x, ws + OFF_L, ws + OFF_MPART, W, Wb, ws);
    k_xm_mean<<<  32, 512, 0, stream>>>(ws);
    k_cov    <<< 544, 256, 0, stream>>>(ws);
    k_chol   <<<  32, 512, 0, stream>>>(ws);
    k_tail   <<< 256, 512, 0, stream>>>(ws, Wb, out);
}